// Round 9
// baseline (3993.939 us; speedup 1.0000x reference)
//
#include <hip/hip_runtime.h>
#include <math.h>

// VanillaRNN, bit-exact (R9-lineage). Numerics FROZEN:
//   * z[i] = ascending-k single FMA chain k=0..255, init 0, split P: k=0..127
//     -> exact float LDS handoff (zpart) -> Q: k=128..255.
//   * z = ((W_hx*x_t) + chain) + bias_h, separately rounded, left-assoc
//   * tanh = Eigen/XLA fast-tanh WITH FMA (clamp 7.99881172180175781f)
//
// R18 — kill the AGPR tax by making parking UNECONOMICAL (tie-pins).
//   Ledger (VALU busy cyc/SIMD/u-iter): R9 2322, R15 2347, R16 2294,
//   R17 2302, R14 3337 (=2322+512 RL). Pure FMA issue = 1024. Constant
//   +~1050 = one v_accvgpr_read per chain FMA: w AGPR-parked every round
//   (VGPR_Count 76-88 with 128 live w); CDNA VALU can't encode AGPR srcs.
//   R17's read-only "v" let the RA park at 1 copy/use. Fix:
//     asm("" : "+v"(w[k])) BEFORE each use — w[k] is REDEFINED in an arch
//     VGPR per use; parking now costs read+write-back (2 copies/use) vs 0
//     for arch residence (128 w + ~50 work = ~180 <= 256 at 2 waves/EU).
//     amdgpu_waves_per_eu(2,2) caps the RA's occupancy target at the
//     2-wave budget so it doesn't chase 128-reg occupancy.
//   Transport reverted to R14's 64BC+64RL (no hg/KINV/store-drain): in the
//   post-tax regime VALU ~900/phase, LDS ~925/phase, chain latency 512 —
//   balanced. (R14's regression was the tax+RL stacking on VALU, not RL.)
//   Transport & pins are value-neutral: same floats, same ascending-k
//   left-assoc order => bit-exact.
// Skeleton = R9 verbatim: literal-offset x2-unrolled STEP (R10 lesson).
// Schedule (audited): phaseA(u): P(col0,u,rp) | Q(col1,u-1,rp^1) [u>=1];
// phaseB(u): P(col1,u,rp) | Q(col0,u,rp); drain Q(col1,TT-1,0); rp=(u&1)^1.

#define TT 2048
#define BB 512
#define HH 256
#define CC 10
#define KH 128   // chain half-length per thread group

__device__ __forceinline__ float ref_tanhf(float x)
{
    const float a1  = 4.89352455891786e-03f;
    const float a3  = 6.37261928875436e-04f;
    const float a5  = 1.48572235717979e-05f;
    const float a7  = 5.12229709037114e-08f;
    const float a9  = -8.60467152213735e-11f;
    const float a11 = 2.00018790482477e-13f;
    const float a13 = -2.76076847742355e-16f;
    const float b0  = 4.89352518554385e-03f;
    const float b2  = 2.26843463243900e-03f;
    const float b4  = 1.18534705686654e-04f;
    const float b6  = 1.19825839466702e-06f;

    const float kClamp = 7.99881172180175781f;
    const float xc = fmaxf(fminf(x, kClamp), -kClamp);
    const float x2 = __fmul_rn(xc, xc);
    float p = fmaf(x2, a13, a11);
    p = fmaf(x2, p, a9);
    p = fmaf(x2, p, a7);
    p = fmaf(x2, p, a5);
    p = fmaf(x2, p, a3);
    p = fmaf(x2, p, a1);
    p = __fmul_rn(xc, p);
    float q = fmaf(x2, b6, b4);
    q = fmaf(x2, q, b2);
    q = fmaf(x2, q, b0);
    const float r = __fdiv_rn(p, q);
    return (fabsf(x) < 0.0004f) ? x : r;
}

__global__ __launch_bounds__(512, 2)
__attribute__((amdgpu_waves_per_eu(2, 2)))
void rnn_fwd(const float* __restrict__ x,
             const float* __restrict__ W_hx,
             const float* __restrict__ W_hh,
             const float* __restrict__ W_ph,
             const float* __restrict__ bias_h,
             const float* __restrict__ bias_p,
             float* __restrict__ out)
{
    const int tid   = threadIdx.x;
    const int group = tid >> 8;        // 0 = P (k 0..127), 1 = Q (k 128..255)
    const int i     = tid & (HH - 1);  // hidden row
    const int l     = tid & 63;        // lane id (preload layout)
    const int b0    = blockIdx.x * 2;  // two batch columns per WG

    __shared__ __align__(16) float xls[2][TT];        // 16 KB
    __shared__ __align__(16) float hbuf[2][2][HH];    // [col][parity][row] 4 KB
    __shared__ __align__(16) float zpart[2][HH];      // 2 KB

    // --- stage: this thread's half-row of W_hh -> 128 regs ---
    float w[KH];
    const float* __restrict__ wrow = W_hh + (size_t)i * HH + group * KH;
#pragma unroll
    for (int k = 0; k < KH; k += 4) {
        const float4 v = *reinterpret_cast<const float4*>(wrow + k);
        w[k] = v.x; w[k + 1] = v.y; w[k + 2] = v.z; w[k + 3] = v.w;
    }
#pragma unroll
    for (int k = 0; k < KH; ++k) {
        asm volatile("" : "+v"(w[k]));   // block rematerialization
    }

    // --- stage: x rows (2*TT contiguous floats) -> LDS, 512 threads ---
    {
        const float4* __restrict__ xsrc =
            reinterpret_cast<const float4*>(x + (size_t)b0 * TT);
        float4* __restrict__ xdst = reinterpret_cast<float4*>(&xls[0][0]);
        xdst[tid]       = xsrc[tid];
        xdst[512 + tid] = xsrc[512 + tid];
    }
    const float whx = W_hx[i];     // used by Q only
    const float bh  = bias_h[i];   // used by Q only

    // h(-1)=0 at parity 1 (step t reads (t&1)^1, writes t&1)
    hbuf[group][1][i] = 0.0f;
    __syncthreads();

// tie-pin + chain FMA: w[K] is redefined in an arch VGPR at the use point.
// AGPR-parking would cost accvgpr_read + write-back per use -> RA keeps
// w arch-resident. fmaf stays plain C (scheduler freedom). Bit-exact.
#define TFMA(K, HV)                                                           \
    {                                                                         \
        asm("" : "+v"(w[(K)]));                                               \
        z = fmaf(w[(K)], (HV), z);                                            \
    }

// readlane of a preloaded h component (uniform -> SGPR operand in the FMA)
#define RLF(V, L) __int_as_float(__builtin_amdgcn_readlane(__float_as_int(V), (L)))

// 4 chain FMAs, h via readlane from preload hq; lane = LB + (KL>>2), literal.
#define RL4(KL, LB)                                                           \
    {                                                                         \
        TFMA((KL) + 0, RLF(hq.x, (LB) + ((KL) >> 2)))                         \
        TFMA((KL) + 1, RLF(hq.y, (LB) + ((KL) >> 2)))                         \
        TFMA((KL) + 2, RLF(hq.z, (LB) + ((KL) >> 2)))                         \
        TFMA((KL) + 3, RLF(hq.w, (LB) + ((KL) >> 2)))                         \
    }
#define RL16(KL, LB) RL4((KL), LB) RL4((KL) + 4, LB) RL4((KL) + 8, LB) RL4((KL) + 12, LB)

// 4 chain FMAs, h via broadcast ds_read_b128 at literal offset HB+KL.
#define BC4(KL, HB)                                                           \
    {                                                                         \
        const float4 h4 = *reinterpret_cast<const float4*>(h + (HB) + (KL));  \
        TFMA((KL) + 0, h4.x)                                                  \
        TFMA((KL) + 1, h4.y)                                                  \
        TFMA((KL) + 2, h4.z)                                                  \
        TFMA((KL) + 3, h4.w)                                                  \
    }
#define BC16(KL, HB) BC4((KL), HB) BC4((KL) + 4, HB) BC4((KL) + 8, HB) BC4((KL) + 12, HB)

// P half-chain: k = 0..127, init 0, store exact partial.
// Preload: lane l holds h[4l..4l+3] (one lane-distinct b128; wave = all h).
// Alternate BC16 (LDS pipe) / RL16 (VALU pipe), ascending k (bit-exact).
#define PBODY(COL, T, RP)                                                     \
    {                                                                         \
        const float* __restrict__ h = &hbuf[(COL)][(RP)][0];                  \
        const float4 hq = reinterpret_cast<const float4*>(h)[l];              \
        float z = 0.0f;                                                       \
        BC16(0, 0)    RL16(16, 0)                                             \
        BC16(32, 0)   RL16(48, 0)                                             \
        BC16(64, 0)   RL16(80, 0)                                             \
        BC16(96, 0)   RL16(112, 0)                                            \
        zpart[(COL)][i] = z;                                                  \
    }

// Q half-chain: resume k = 128..255 (local j = k-128), then x/bias/tanh,
// write parity RP^1. RL lanes offset by 32 (global k = 128 + j).
#define QBODY(COL, T, RP)                                                     \
    {                                                                         \
        const float* __restrict__ h = &hbuf[(COL)][(RP)][0];                  \
        const float4 hq = reinterpret_cast<const float4*>(h)[l];              \
        float z = zpart[(COL)][i];                                            \
        BC16(0, KH)    RL16(16, 32)                                           \
        BC16(32, KH)   RL16(48, 32)                                           \
        BC16(64, KH)   RL16(80, 32)                                           \
        BC16(96, KH)   RL16(112, 32)                                          \
        const float a0 = __fmul_rn(whx, xls[(COL)][(T)]);                     \
        z = __fadd_rn(__fadd_rn(a0, z), bh);                                  \
        hbuf[(COL)][(RP) ^ 1][i] = ref_tanhf(z);                              \
    }

// One u-iteration with compile-time read-parity RP = (u&1)^1.
#define STEP(U, RP)                                                           \
    {                                                                         \
        if (group == 0) { PBODY(0, (U), (RP)) }                               \
        else if ((U) >= 1) { QBODY(1, (U) - 1, (RP) ^ 1) }                    \
        __syncthreads();                                                      \
        if (group == 0) { PBODY(1, (U), (RP)) }                               \
        else { QBODY(0, (U), (RP)) }                                          \
        __syncthreads();                                                      \
    }

    // u=0 peeled (resolves the u>=1 guard), then pairs with constant parity.
    STEP(0, 1)
    for (int u = 1; u + 1 < TT; u += 2) {
        STEP(u, 0)
        STEP(u + 1, 1)
    }
    STEP(TT - 1, 0)                       // u = 2047 (odd -> rp = 0)
    if (group == 1) { QBODY(1, TT - 1, 0) }   // drain pipeline: col1, last step
    __syncthreads();

#undef STEP
#undef QBODY
#undef PBODY
#undef BC16
#undef BC4
#undef RL16
#undef RL4
#undef RLF
#undef TFMA

    // epilogue: p[b,c] = sum_k h_T[k]*W_ph[c,k] + bias_p[c]
    // last step t = TT-1 wrote parity (TT-1)&1 = 1
    if (tid < 2 * CC) {
        const int col = tid / CC;
        const int c   = tid % CC;
        const float* __restrict__ wp = W_ph + (size_t)c * HH;
        const float* __restrict__ hf = hbuf[col][1];
        float pv = 0.0f;
#pragma unroll 8
        for (int k = 0; k < HH; ++k) {
            pv = fmaf(hf[k], wp[k], pv);
        }
        out[(size_t)(b0 + col) * CC + c] = __fadd_rn(pv, bias_p[c]);
    }
}

extern "C" void kernel_launch(void* const* d_in, const int* in_sizes, int n_in,
                              void* d_out, int out_size, void* d_ws, size_t ws_size,
                              hipStream_t stream) {
    const float* x      = (const float*)d_in[0];
    const float* W_hx   = (const float*)d_in[1];
    const float* W_hh   = (const float*)d_in[2];
    const float* W_ph   = (const float*)d_in[3];
    const float* bias_h = (const float*)d_in[4];
    const float* bias_p = (const float*)d_in[5];
    float* out = (float*)d_out;

    rnn_fwd<<<dim3(BB / 2), dim3(512), 0, stream>>>(x, W_hx, W_hh, W_ph, bias_h, bias_p, out);
}